// Round 3
// baseline (8262.586 us; speedup 1.0000x reference)
//
#include <hip/hip_runtime.h>
#include <hip/hip_bf16.h>
#include <math.h>

#define DIM   512
#define HIDW  256
#define ATTW  128
#define MAXC  50
#define BLK   256
#define BUFW  132
#define SB_W  52
#define CH    10
#define SCL   0.08838834764831845f  // 1/sqrt(128)

__device__ __forceinline__ float bf2f(ushort u){ union{unsigned i;float f;}v; v.i=((unsigned)u)<<16; return v.f; }
__device__ __forceinline__ ushort f2bf(float f){
  union{float f;unsigned i;}v; v.f=f;
  unsigned r = v.i + 0x7fffu + ((v.i>>16)&1u);
  return (ushort)(r>>16);
}

template<bool F32>
__device__ __forceinline__ float ld(const void* p, int i){
  if (F32) return ((const float*)p)[i];
  return bf2f(((const ushort*)p)[i]);
}

struct P27 {
  const void *molA, *nodeH; const int* counts;
  const void *wq1,*bq1,*wq2,*bq2, *wk1,*bk1,*wk2,*bk2, *wv1,*bv1,*wv2,*bv2;
  const void *uk1,*ubk1,*uk2,*ubk2, *uq1,*ubq1,*uq2,*ubq2;
  const void *cs1,*bcs1,*cs2,*bcs2;
  void* out;
};

// ---------- prep: dtype detect + exclusive scan of counts ----------
__global__ void prep_kernel(const ushort* __restrict__ molAu,
                            const int* __restrict__ counts, int nb,
                            int* __restrict__ wsInt)
{
  __shared__ int part[BLK];
  __shared__ int cnt;
  const int t = threadIdx.x;
  if (t == 0) cnt = 0;
  __syncthreads();
  int e = (molAu[t] >> 7) & 0xFF;           // bf16 exponent field
  if (e >= 100 && e <= 140) atomicAdd(&cnt, 1);
  const int per = (nb + BLK - 1) / BLK;
  int s = 0;
  for (int i = 0; i < per; i++) { int idx = t*per + i; if (idx < nb) s += counts[idx]; }
  part[t] = s;
  __syncthreads();
  if (t == 0) {
    int run = 0;
    for (int i = 0; i < BLK; i++) { int v = part[i]; part[i] = run; run += v; }
    wsInt[0] = (cnt >= 220) ? 0 : 1;        // 0 = bf16 inputs, 1 = f32 inputs
  }
  __syncthreads();
  int run = part[t];
  for (int i = 0; i < per; i++) {
    int idx = t*per + i;
    if (idx < nb) { wsInt[4 + idx] = run; run += counts[idx]; }
  }
}

// stage1 from global x (din=512 -> 256, relu). Rows >= c use x=0 (index clamped, like ref's clip).
template<bool F32>
__device__ void stage1_g(const void* X, int xb, int c,
                         const void* W, const void* Bv, ushort* hl, int t)
{
  for (int r0 = 0; r0 < MAXC; r0 += CH) {
    float acc[CH];
#pragma unroll
    for (int i = 0; i < CH; i++) acc[i] = 0.f;
    for (int k = 0; k < DIM; k++) {
      float wv = ld<F32>(W, k*HIDW + t);
#pragma unroll
      for (int i = 0; i < CH; i++) {
        int m = r0 + i;
        int mc = (m < c) ? m : 0;               // clamp: always in-bounds
        float xv = ld<F32>(X, xb + mc*DIM + k);
        acc[i] += ((m < c) ? xv : 0.f) * wv;
      }
    }
    float bb = ld<F32>(Bv, t);
#pragma unroll
    for (int i = 0; i < CH; i++)
      hl[(r0+i)*HIDW + t] = f2bf(fmaxf(acc[i] + bb, 0.f));
  }
}

// stage1 from LDS rows (din=128, stride BUFW -> 256, relu). All MAXC rows valid.
template<bool F32>
__device__ void stage1_l(const ushort* S, const void* W, const void* Bv,
                         ushort* hl, int t)
{
  for (int r0 = 0; r0 < MAXC; r0 += CH) {
    float acc[CH];
#pragma unroll
    for (int i = 0; i < CH; i++) acc[i] = 0.f;
    for (int k = 0; k < ATTW; k++) {
      float wv = ld<F32>(W, k*HIDW + t);
#pragma unroll
      for (int i = 0; i < CH; i++)
        acc[i] += bf2f(S[(r0+i)*BUFW + k]) * wv;
    }
    float bb = ld<F32>(Bv, t);
#pragma unroll
    for (int i = 0; i < CH; i++)
      hl[(r0+i)*HIDW + t] = f2bf(fmaxf(acc[i] + bb, 0.f));
  }
}

// stage2: hl (MAXC x 256) @ W(256x128) + b -> dst (MAXC x BUFW), no activation.
template<bool F32>
__device__ void stage2(const void* W, const void* Bv, const ushort* hlp,
                       ushort* dst, int t)
{
  const int col = t & (ATTW-1);
  const int h = t >> 7;
  float bb = ld<F32>(Bv, col);
  for (int m = h; m < MAXC; m += 2) {
    float a = 0.f;
    for (int k = 0; k < HIDW; k++)
      a += bf2f(hlp[m*HIDW + k]) * ld<F32>(W, k*ATTW + col);
    dst[m*BUFW + col] = f2bf(a + bb);
  }
}

template<bool F32>
__device__ void body(const P27& P, int b, int t,
                     ushort* hl, ushort* buf0, ushort* buf1, float* sb,
                     float* q2h, float* q2, float* logit, float* selh,
                     int offset, int c)
{
  const int xb = offset * DIM;

  // K
  stage1_g<F32>(P.nodeH, xb, c, P.wk1, P.bk1, hl, t);
  __syncthreads();
  stage2<F32>(P.wk2, P.bk2, hl, buf0, t);
  __syncthreads();
  // Q
  stage1_g<F32>(P.nodeH, xb, c, P.wq1, P.bq1, hl, t);
  __syncthreads();
  stage2<F32>(P.wq2, P.bq2, hl, buf1, t);
  __syncthreads();

  // scores: full 50x50, mask exactly like reference, then *SCL
  for (int idx = t; idx < MAXC*MAXC; idx += BLK) {
    int m = idx / MAXC, n = idx - m*MAXC;
    float s;
    if (m < c && n < c) {
      s = 0.f;
      for (int k = 0; k < ATTW; k++)
        s += bf2f(buf0[m*BUFW + k]) * bf2f(buf1[n*BUFW + k]);
    } else {
      s = -1e9f;
    }
    sb[m*SB_W + n] = s * SCL;
  }
  __syncthreads();
  // softmax over all 50 cols for all 50 rows (pads handled exactly like ref)
  if (t < MAXC) {
    float* row = sb + t*SB_W;
    float mx = row[0];
    for (int n = 1; n < MAXC; n++) mx = fmaxf(mx, row[n]);
    float sum = 0.f;
    for (int n = 0; n < MAXC; n++) { float e = expf(row[n] - mx); row[n] = e; sum += e; }
    float inv = 1.f / sum;
    for (int n = 0; n < MAXC; n++) row[n] *= inv;
  }
  __syncthreads();

  // V
  stage1_g<F32>(P.nodeH, xb, c, P.wv1, P.bv1, hl, t);
  __syncthreads();
  stage2<F32>(P.wv2, P.bv2, hl, buf0, t);
  __syncthreads();

  // corr = attn @ V -> buf1 (full 50x50, no special cases)
  {
    const int col = t & (ATTW-1);
    const int h = t >> 7;
    for (int m = h; m < MAXC; m += 2) {
      float a = 0.f;
      for (int n = 0; n < MAXC; n++)
        a += sb[m*SB_W + n] * bf2f(buf0[n*BUFW + col]);
      buf1[m*BUFW + col] = f2bf(a);
    }
  }
  __syncthreads();

  // K2
  stage1_l<F32>(buf1, P.uk1, P.ubk1, hl, t);
  __syncthreads();
  stage2<F32>(P.uk2, P.ubk2, hl, buf0, t);
  __syncthreads();

  // Q2
  {
    float a = 0.f;
    for (int k = 0; k < DIM; k++)
      a += ld<F32>(P.molA, b*DIM + k) * ld<F32>(P.uq1, k*HIDW + t);
    q2h[t] = fmaxf(a + ld<F32>(P.ubq1, t), 0.f);
  }
  __syncthreads();
  if (t < ATTW) {
    float a = 0.f;
    for (int k = 0; k < HIDW; k++)
      a += q2h[k] * ld<F32>(P.uq2, k*ATTW + t);
    q2[t] = a + ld<F32>(P.ubq2, t);
  }
  __syncthreads();

  // logits (all 50 rows, pads included naturally)
  if (t < MAXC) {
    float s = 0.f;
    for (int k = 0; k < ATTW; k++)
      s += bf2f(buf0[t*BUFW + k]) * q2[k];
    logit[t] = s * SCL;
  }
  __syncthreads();

  // sel MLP
  if (t < ATTW) {
    float a = 0.f;
    for (int k = 0; k < MAXC; k++)
      a += logit[k] * ld<F32>(P.cs1, k*ATTW + t);
    selh[t] = fmaxf(a + ld<F32>(P.bcs1, t), 0.f);
  }
  __syncthreads();
  if (t < c) {
    float a = 0.f;
    for (int k = 0; k < ATTW; k++)
      a += selh[k] * ld<F32>(P.cs2, k*MAXC + t);
    a += ld<F32>(P.bcs2, t);
    float v = 1.f / (1.f + expf(-a));
    if (F32) ((float*)P.out)[offset + t] = v;
    else     ((ushort*)P.out)[offset + t] = f2bf(v);
  }
}

__global__ void fused_kernel(P27 P, const int* __restrict__ wsInt)
{
  __shared__ __align__(16) ushort hl  [MAXC*HIDW];
  __shared__ __align__(16) ushort buf0[MAXC*BUFW];
  __shared__ __align__(16) ushort buf1[MAXC*BUFW];
  __shared__ __align__(16) float  sb  [MAXC*SB_W];
  __shared__ __align__(16) float  q2h [HIDW];
  __shared__ __align__(16) float  q2  [ATTW];
  __shared__ __align__(16) float  logit[64];
  __shared__ __align__(16) float  selh[ATTW];

  const int t = threadIdx.x;
  const int b = blockIdx.x;
  const int f32m  = wsInt[0];
  const int offset = wsInt[4 + b];
  const int c = P.counts[b];

  if (f32m) body<true >(P, b, t, hl, buf0, buf1, sb, q2h, q2, logit, selh, offset, c);
  else      body<false>(P, b, t, hl, buf0, buf1, sb, q2h, q2, logit, selh, offset, c);
}

extern "C" void kernel_launch(void* const* d_in, const int* in_sizes, int n_in,
                              void* d_out, int out_size, void* d_ws, size_t ws_size,
                              hipStream_t stream) {
  P27 P;
  P.molA  = d_in[0];
  P.nodeH = d_in[1];
  P.counts= (const int*)d_in[2];
  P.wq1 = d_in[3];  P.bq1 = d_in[4];  P.wq2 = d_in[5];  P.bq2 = d_in[6];
  P.wk1 = d_in[7];  P.bk1 = d_in[8];  P.wk2 = d_in[9];  P.bk2 = d_in[10];
  P.wv1 = d_in[11]; P.bv1 = d_in[12]; P.wv2 = d_in[13]; P.bv2 = d_in[14];
  P.uk1 = d_in[15]; P.ubk1= d_in[16]; P.uk2 = d_in[17]; P.ubk2= d_in[18];
  P.uq1 = d_in[19]; P.ubq1= d_in[20]; P.uq2 = d_in[21]; P.ubq2= d_in[22];
  P.cs1 = d_in[23]; P.bcs1= d_in[24]; P.cs2 = d_in[25]; P.bcs2= d_in[26];
  P.out = d_out;
  const int nb = in_sizes[2];
  int* wsInt = (int*)d_ws;

  prep_kernel<<<dim3(1), dim3(BLK), 0, stream>>>((const ushort*)d_in[0],
                                                 (const int*)d_in[2], nb, wsInt);
  fused_kernel<<<dim3(nb), dim3(BLK), 0, stream>>>(P, wsInt);
}

// Round 7
// 2904.661 us; speedup vs baseline: 2.8446x; 2.8446x over previous
//
#include <hip/hip_runtime.h>
#include <hip/hip_bf16.h>
#include <math.h>

#define DIM   512
#define HIDW  256
#define ATTW  128
#define MAXC  50
#define BLK   256
#define BUFW  132
#define SB_W  52
#define CH    10
#define SCL   0.08838834764831845f  // 1/sqrt(128)

typedef float f32x4 __attribute__((ext_vector_type(4)));
typedef short s16x8 __attribute__((ext_vector_type(8)));

__device__ __forceinline__ float bf2f(ushort u){ union{unsigned i;float f;}v; v.i=((unsigned)u)<<16; return v.f; }
__device__ __forceinline__ ushort f2bf(float f){
  union{float f;unsigned i;}v; v.f=f;
  unsigned r = v.i + 0x7fffu + ((v.i>>16)&1u);
  return (ushort)(r>>16);
}
__device__ __forceinline__ s16x8 ldfrag(const ushort* p){ s16x8 v; __builtin_memcpy(&v, p, 16); return v; }
__device__ __forceinline__ f32x4 mfma16(s16x8 a, s16x8 b, f32x4 c){
  return __builtin_amdgcn_mfma_f32_16x16x32_bf16(a, b, c, 0, 0, 0);
}

template<bool F32>
__device__ __forceinline__ float ld(const void* p, int i){
  if (F32) return ((const float*)p)[i];
  return bf2f(((const ushort*)p)[i]);
}

struct P27 {
  const void *molA, *nodeH; const int* counts;
  const void *wq1,*bq1,*wq2,*bq2, *wk1,*bk1,*wk2,*bk2, *wv1,*bv1,*wv2,*bv2;
  const void *uk1,*ubk1,*uk2,*ubk2, *uq1,*ubq1,*uq2,*ubq2;
  const void *cs1,*bcs1,*cs2,*bcs2;
  void* out;
};

// workspace: wsInt[0]=f32flag, wsInt[4..4+nb) offsets; wt (bf16) at byte 8704
#define O_WK1T 0
#define O_WQ1T 131072
#define O_WV1T 262144
#define WT_ELEMS 393216
#define WT_BYTE_OFF 8704

// ---------- prep: dtype detect + exclusive scan (VERBATIM r2, validated) ----------
__global__ void prep_kernel(const ushort* __restrict__ molAu,
                            const int* __restrict__ counts, int nb,
                            int* __restrict__ wsInt)
{
  __shared__ int part[BLK];
  __shared__ int cnt;
  const int t = threadIdx.x;
  if (t == 0) cnt = 0;
  __syncthreads();
  int e = (molAu[t] >> 7) & 0xFF;           // bf16 exponent field
  if (e >= 100 && e <= 140) atomicAdd(&cnt, 1);
  const int per = (nb + BLK - 1) / BLK;
  int s = 0;
  for (int i = 0; i < per; i++) { int idx = t*per + i; if (idx < nb) s += counts[idx]; }
  part[t] = s;
  __syncthreads();
  if (t == 0) {
    int run = 0;
    for (int i = 0; i < BLK; i++) { int v = part[i]; part[i] = run; run += v; }
    wsInt[0] = (cnt >= 220) ? 0 : 1;        // 0 = bf16 inputs, 1 = f32 inputs
  }
  __syncthreads();
  int run = part[t];
  for (int i = 0; i < per; i++) {
    int idx = t*per + i;
    if (idx < nb) { wsInt[4 + idx] = run; run += counts[idx]; }
  }
}

// ---------- prep: transpose+convert wk1/wq1/wv1 (512x256) -> bf16 (256x512) ----------
__global__ void transpose_w1(const void* __restrict__ wk1, const void* __restrict__ wq1,
                             const void* __restrict__ wv1, const int* __restrict__ wsInt,
                             ushort* __restrict__ wt, unsigned long long cap_elems)
{
  unsigned i = blockIdx.x*BLK + threadIdx.x;
  if (i >= WT_ELEMS) return;
  if ((unsigned long long)i >= cap_elems) return;
  const int f32m = wsInt[0];
  int m = i / 131072;
  int j = i - m*131072;
  int n = j >> 9;            // output feature 0..255
  int k = j & 511;           // input dim 0..511
  const void* src = (m==0) ? wk1 : ((m==1) ? wq1 : wv1);
  float v = f32m ? ((const float*)src)[k*HIDW + n] : bf2f(((const ushort*)src)[k*HIDW + n]);
  wt[i] = f2bf(v);
}

// ---------- MFMA stage1: X rows (pads=0) @ W1t + b1, relu -> hl[50x256] bf16 ----------
template<bool F32>
__device__ __forceinline__ void stage1_mfma(const void* __restrict__ X, int xb, int c,
                                            const ushort* __restrict__ Wt,   // 256x512 bf16
                                            const void* __restrict__ Bv,     // 256
                                            ushort* __restrict__ hl, int t)
{
  const int w = t >> 6, L = t & 63, quad = L >> 4, l16 = L & 15;
  f32x4 acc[4][4];
#pragma unroll
  for (int i = 0; i < 4; i++)
#pragma unroll
    for (int j = 0; j < 4; j++) acc[i][j] = (f32x4){0.f,0.f,0.f,0.f};

  bool va[4]; int rr[4];
#pragma unroll
  for (int mt = 0; mt < 4; mt++) {
    int row = mt*16 + l16;
    va[mt] = (row < c);
    rr[mt] = va[mt] ? row : 0;
  }
  const ushort* pB = Wt + (size_t)(w*64 + l16)*DIM + quad*8;

  for (int k0 = 0; k0 < DIM; k0 += 32) {
    s16x8 a[4];
#pragma unroll
    for (int mt = 0; mt < 4; mt++) {
      s16x8 z = {};
      if (va[mt]) {
        if (F32) {
          const float* xp = (const float*)X + xb + rr[mt]*DIM + k0 + quad*8;
          s16x8 v;
#pragma unroll
          for (int j = 0; j < 8; j++) v[j] = (short)f2bf(xp[j]);
          a[mt] = v;
        } else {
          a[mt] = ldfrag((const ushort*)X + xb + rr[mt]*DIM + k0 + quad*8);
        }
      } else a[mt] = z;
    }
#pragma unroll
    for (int nt = 0; nt < 4; nt++) {
      s16x8 b = ldfrag(pB + (size_t)nt*16*DIM + k0);
#pragma unroll
      for (int mt = 0; mt < 4; mt++)
        acc[mt][nt] = mfma16(a[mt], b, acc[mt][nt]);
    }
  }
#pragma unroll
  for (int nt = 0; nt < 4; nt++) {
    int col = w*64 + nt*16 + l16;
    float bb = ld<F32>(Bv, col);
#pragma unroll
    for (int mt = 0; mt < 4; mt++)
#pragma unroll
      for (int r = 0; r < 4; r++) {
        int row = mt*16 + quad*4 + r;
        if (row < MAXC)
          hl[row*HIDW + col] = f2bf(fmaxf(acc[mt][nt][r] + bb, 0.f));
      }
  }
}

// ---------- scalar stage1 from global (VERBATIM r2, for fallback) ----------
template<bool F32>
__device__ void stage1_g(const void* X, int xb, int c,
                         const void* W, const void* Bv, ushort* hl, int t)
{
  for (int r0 = 0; r0 < MAXC; r0 += CH) {
    float acc[CH];
#pragma unroll
    for (int i = 0; i < CH; i++) acc[i] = 0.f;
    for (int k = 0; k < DIM; k++) {
      float wv = ld<F32>(W, k*HIDW + t);
#pragma unroll
      for (int i = 0; i < CH; i++) {
        int m = r0 + i;
        int mc = (m < c) ? m : 0;
        float xv = ld<F32>(X, xb + mc*DIM + k);
        acc[i] += ((m < c) ? xv : 0.f) * wv;
      }
    }
    float bb = ld<F32>(Bv, t);
#pragma unroll
    for (int i = 0; i < CH; i++)
      hl[(r0+i)*HIDW + t] = f2bf(fmaxf(acc[i] + bb, 0.f));
  }
}

// ---------- scalar stage1 from LDS (VERBATIM r2) ----------
template<bool F32>
__device__ void stage1_l(const ushort* S, const void* W, const void* Bv,
                         ushort* hl, int t)
{
  for (int r0 = 0; r0 < MAXC; r0 += CH) {
    float acc[CH];
#pragma unroll
    for (int i = 0; i < CH; i++) acc[i] = 0.f;
    for (int k = 0; k < ATTW; k++) {
      float wv = ld<F32>(W, k*HIDW + t);
#pragma unroll
      for (int i = 0; i < CH; i++)
        acc[i] += bf2f(S[(r0+i)*BUFW + k]) * wv;
    }
    float bb = ld<F32>(Bv, t);
#pragma unroll
    for (int i = 0; i < CH; i++)
      hl[(r0+i)*HIDW + t] = f2bf(fmaxf(acc[i] + bb, 0.f));
  }
}

// ---------- scalar stage2 (VERBATIM r2) ----------
template<bool F32>
__device__ void stage2(const void* W, const void* Bv, const ushort* hlp,
                       ushort* dst, int t)
{
  const int col = t & (ATTW-1);
  const int h = t >> 7;
  float bb = ld<F32>(Bv, col);
  for (int m = h; m < MAXC; m += 2) {
    float a = 0.f;
    for (int k = 0; k < HIDW; k++)
      a += bf2f(hlp[m*HIDW + k]) * ld<F32>(W, k*ATTW + col);
    dst[m*BUFW + col] = f2bf(a + bb);
  }
}

// ---------- body: VERBATIM r2 except optional MFMA stage1 for K/Q/V ----------
template<bool F32, bool MF>
__device__ void body(const P27& P, int b, int t,
                     ushort* hl, ushort* buf0, ushort* buf1, float* sb,
                     float* q2h, float* q2, float* logit, float* selh,
                     int offset, int c, const ushort* wt)
{
  const int xb = offset * DIM;

  // K
  if (MF) stage1_mfma<F32>(P.nodeH, xb, c, wt + O_WK1T, P.bk1, hl, t);
  else    stage1_g<F32>(P.nodeH, xb, c, P.wk1, P.bk1, hl, t);
  __syncthreads();
  stage2<F32>(P.wk2, P.bk2, hl, buf0, t);
  __syncthreads();
  // Q
  if (MF) stage1_mfma<F32>(P.nodeH, xb, c, wt + O_WQ1T, P.bq1, hl, t);
  else    stage1_g<F32>(P.nodeH, xb, c, P.wq1, P.bq1, hl, t);
  __syncthreads();
  stage2<F32>(P.wq2, P.bq2, hl, buf1, t);
  __syncthreads();

  // scores: full 50x50, mask exactly like reference, then *SCL
  for (int idx = t; idx < MAXC*MAXC; idx += BLK) {
    int m = idx / MAXC, n = idx - m*MAXC;
    float s;
    if (m < c && n < c) {
      s = 0.f;
      for (int k = 0; k < ATTW; k++)
        s += bf2f(buf0[m*BUFW + k]) * bf2f(buf1[n*BUFW + k]);
    } else {
      s = -1e9f;
    }
    sb[m*SB_W + n] = s * SCL;
  }
  __syncthreads();
  if (t < MAXC) {
    float* row = sb + t*SB_W;
    float mx = row[0];
    for (int n = 1; n < MAXC; n++) mx = fmaxf(mx, row[n]);
    float sum = 0.f;
    for (int n = 0; n < MAXC; n++) { float e = expf(row[n] - mx); row[n] = e; sum += e; }
    float inv = 1.f / sum;
    for (int n = 0; n < MAXC; n++) row[n] *= inv;
  }
  __syncthreads();

  // V
  if (MF) stage1_mfma<F32>(P.nodeH, xb, c, wt + O_WV1T, P.bv1, hl, t);
  else    stage1_g<F32>(P.nodeH, xb, c, P.wv1, P.bv1, hl, t);
  __syncthreads();
  stage2<F32>(P.wv2, P.bv2, hl, buf0, t);
  __syncthreads();

  // corr = attn @ V -> buf1
  {
    const int col = t & (ATTW-1);
    const int h = t >> 7;
    for (int m = h; m < MAXC; m += 2) {
      float a = 0.f;
      for (int n = 0; n < MAXC; n++)
        a += sb[m*SB_W + n] * bf2f(buf0[n*BUFW + col]);
      buf1[m*BUFW + col] = f2bf(a);
    }
  }
  __syncthreads();

  // K2
  stage1_l<F32>(buf1, P.uk1, P.ubk1, hl, t);
  __syncthreads();
  stage2<F32>(P.uk2, P.ubk2, hl, buf0, t);
  __syncthreads();

  // Q2
  {
    float a = 0.f;
    for (int k = 0; k < DIM; k++)
      a += ld<F32>(P.molA, b*DIM + k) * ld<F32>(P.uq1, k*HIDW + t);
    q2h[t] = fmaxf(a + ld<F32>(P.ubq1, t), 0.f);
  }
  __syncthreads();
  if (t < ATTW) {
    float a = 0.f;
    for (int k = 0; k < HIDW; k++)
      a += q2h[k] * ld<F32>(P.uq2, k*ATTW + t);
    q2[t] = a + ld<F32>(P.ubq2, t);
  }
  __syncthreads();

  if (t < MAXC) {
    float s = 0.f;
    for (int k = 0; k < ATTW; k++)
      s += bf2f(buf0[t*BUFW + k]) * q2[k];
    logit[t] = s * SCL;
  }
  __syncthreads();

  if (t < ATTW) {
    float a = 0.f;
    for (int k = 0; k < MAXC; k++)
      a += logit[k] * ld<F32>(P.cs1, k*ATTW + t);
    selh[t] = fmaxf(a + ld<F32>(P.bcs1, t), 0.f);
  }
  __syncthreads();
  if (t < c) {
    float a = 0.f;
    for (int k = 0; k < ATTW; k++)
      a += selh[k] * ld<F32>(P.cs2, k*MAXC + t);
    a += ld<F32>(P.bcs2, t);
    float v = 1.f / (1.f + expf(-a));
    if (F32) ((float*)P.out)[offset + t] = v;
    else     ((ushort*)P.out)[offset + t] = f2bf(v);
  }
}

__global__ void fused_mfma(P27 P, const int* __restrict__ wsInt, const ushort* __restrict__ wt)
{
  __shared__ __align__(16) ushort hl  [MAXC*HIDW];
  __shared__ __align__(16) ushort buf0[MAXC*BUFW];
  __shared__ __align__(16) ushort buf1[MAXC*BUFW];
  __shared__ __align__(16) float  sb  [MAXC*SB_W];
  __shared__ __align__(16) float  q2h [HIDW];
  __shared__ __align__(16) float  q2  [ATTW];
  __shared__ __align__(16) float  logit[64];
  __shared__ __align__(16) float  selh[ATTW];

  const int t = threadIdx.x, b = blockIdx.x;
  const int f32m = wsInt[0];
  const int offset = wsInt[4 + b];
  const int c = P.counts[b];

  if (f32m) body<true , true>(P, b, t, hl, buf0, buf1, sb, q2h, q2, logit, selh, offset, c, wt);
  else      body<false, true>(P, b, t, hl, buf0, buf1, sb, q2h, q2, logit, selh, offset, c, wt);
}

__global__ void fused_scalar(P27 P, const int* __restrict__ wsInt)
{
  __shared__ __align__(16) ushort hl  [MAXC*HIDW];
  __shared__ __align__(16) ushort buf0[MAXC*BUFW];
  __shared__ __align__(16) ushort buf1[MAXC*BUFW];
  __shared__ __align__(16) float  sb  [MAXC*SB_W];
  __shared__ __align__(16) float  q2h [HIDW];
  __shared__ __align__(16) float  q2  [ATTW];
  __shared__ __align__(16) float  logit[64];
  __shared__ __align__(16) float  selh[ATTW];

  const int t = threadIdx.x, b = blockIdx.x;
  const int f32m = wsInt[0];
  const int offset = wsInt[4 + b];
  const int c = P.counts[b];

  if (f32m) body<true , false>(P, b, t, hl, buf0, buf1, sb, q2h, q2, logit, selh, offset, c, nullptr);
  else      body<false, false>(P, b, t, hl, buf0, buf1, sb, q2h, q2, logit, selh, offset, c, nullptr);
}

extern "C" void kernel_launch(void* const* d_in, const int* in_sizes, int n_in,
                              void* d_out, int out_size, void* d_ws, size_t ws_size,
                              hipStream_t stream) {
  P27 P;
  P.molA  = d_in[0];
  P.nodeH = d_in[1];
  P.counts= (const int*)d_in[2];
  P.wq1 = d_in[3];  P.bq1 = d_in[4];  P.wq2 = d_in[5];  P.bq2 = d_in[6];
  P.wk1 = d_in[7];  P.bk1 = d_in[8];  P.wk2 = d_in[9];  P.bk2 = d_in[10];
  P.wv1 = d_in[11]; P.bv1 = d_in[12]; P.wv2 = d_in[13]; P.bv2 = d_in[14];
  P.uk1 = d_in[15]; P.ubk1= d_in[16]; P.uk2 = d_in[17]; P.ubk2= d_in[18];
  P.uq1 = d_in[19]; P.ubq1= d_in[20]; P.uq2 = d_in[21]; P.ubq2= d_in[22];
  P.cs1 = d_in[23]; P.bcs1= d_in[24]; P.cs2 = d_in[25]; P.bcs2= d_in[26];
  P.out = d_out;
  const int nb = in_sizes[2];
  int* wsInt = (int*)d_ws;

  prep_kernel<<<dim3(1), dim3(BLK), 0, stream>>>((const ushort*)d_in[0],
                                                 (const int*)d_in[2], nb, wsInt);

  const size_t need = (size_t)WT_BYTE_OFF + (size_t)WT_ELEMS * 2;
  if (ws_size >= need) {
    ushort* wt = (ushort*)((char*)d_ws + WT_BYTE_OFF);
    unsigned long long cap = (ws_size - WT_BYTE_OFF) / 2;
    transpose_w1<<<dim3((WT_ELEMS + BLK - 1)/BLK), dim3(BLK), 0, stream>>>(
        P.wk1, P.wq1, P.wv1, wsInt, wt, cap);
    fused_mfma<<<dim3(nb), dim3(BLK), 0, stream>>>(P, wsInt, wt);
  } else {
    fused_scalar<<<dim3(nb), dim3(BLK), 0, stream>>>(P, wsInt);
  }
}

// Round 8
// 1092.431 us; speedup vs baseline: 7.5635x; 2.6589x over previous
//
#include <hip/hip_runtime.h>
#include <hip/hip_bf16.h>
#include <math.h>

#define DIM   512
#define HIDW  256
#define ATTW  128
#define MAXC  50
#define BLK   256
#define BUFW  136    // K/Q/V/corr/K2 row stride (272B, 16B-aligned, 68dw = +4 banks/row)
#define HL2   264    // hidden row stride for MFMA kernel (528B, 16B-aligned, +4 banks/row)
#define SB_W  52
#define CH    10
#define SCL   0.08838834764831845f  // 1/sqrt(128)

typedef float f32x4 __attribute__((ext_vector_type(4)));
typedef short s16x8 __attribute__((ext_vector_type(8)));

__device__ __forceinline__ float bf2f(ushort u){ union{unsigned i;float f;}v; v.i=((unsigned)u)<<16; return v.f; }
__device__ __forceinline__ ushort f2bf(float f){
  union{float f;unsigned i;}v; v.f=f;
  unsigned r = v.i + 0x7fffu + ((v.i>>16)&1u);
  return (ushort)(r>>16);
}
__device__ __forceinline__ s16x8 ldfrag(const ushort* p){ s16x8 v; __builtin_memcpy(&v, p, 16); return v; }
__device__ __forceinline__ f32x4 mfma16(s16x8 a, s16x8 b, f32x4 c){
  return __builtin_amdgcn_mfma_f32_16x16x32_bf16(a, b, c, 0, 0, 0);
}

template<bool F32>
__device__ __forceinline__ float ld(const void* p, int i){
  if (F32) return ((const float*)p)[i];
  return bf2f(((const ushort*)p)[i]);
}

struct P27 {
  const void *molA, *nodeH; const int* counts;
  const void *wq1,*bq1,*wq2,*bq2, *wk1,*bk1,*wk2,*bk2, *wv1,*bv1,*wv2,*bv2;
  const void *uk1,*ubk1,*uk2,*ubk2, *uq1,*ubq1,*uq2,*ubq2;
  const void *cs1,*bcs1,*cs2,*bcs2;
  void* out;
};

// workspace: wsInt[0]=f32flag, wsInt[4..4+nb) offsets; wt (bf16) at byte 8704
#define O_WK1T 0
#define O_WQ1T 131072
#define O_WV1T 262144
#define O_WK2T 393216
#define O_WQ2T 425984
#define O_WV2T 458752
#define O_UK1T 491520
#define O_UK2T 524288
#define WT_ELEMS   557056
#define WT_T2ELEMS 393216
#define WT_BYTE_OFF 8704

// ---------- prep: dtype detect + exclusive scan (VERBATIM r2/r7, validated) ----------
__global__ void prep_kernel(const ushort* __restrict__ molAu,
                            const int* __restrict__ counts, int nb,
                            int* __restrict__ wsInt)
{
  __shared__ int part[BLK];
  __shared__ int cnt;
  const int t = threadIdx.x;
  if (t == 0) cnt = 0;
  __syncthreads();
  int e = (molAu[t] >> 7) & 0xFF;
  if (e >= 100 && e <= 140) atomicAdd(&cnt, 1);
  const int per = (nb + BLK - 1) / BLK;
  int s = 0;
  for (int i = 0; i < per; i++) { int idx = t*per + i; if (idx < nb) s += counts[idx]; }
  part[t] = s;
  __syncthreads();
  if (t == 0) {
    int run = 0;
    for (int i = 0; i < BLK; i++) { int v = part[i]; part[i] = run; run += v; }
    wsInt[0] = (cnt >= 220) ? 0 : 1;        // 0 = bf16 inputs, 1 = f32 inputs
  }
  __syncthreads();
  int run = part[t];
  for (int i = 0; i < per; i++) {
    int idx = t*per + i;
    if (idx < nb) { wsInt[4 + idx] = run; run += counts[idx]; }
  }
}

// ---------- prep: transpose+convert 8 weight matrices -> bf16 (bounds-guarded) ----------
__global__ void transpose_wt(P27 P, const int* __restrict__ wsInt,
                             ushort* __restrict__ wt, unsigned long long cap_elems)
{
  unsigned i = blockIdx.x*BLK + threadIdx.x;
  if (i >= WT_ELEMS) return;
  if ((unsigned long long)i >= cap_elems) return;
  const int f32m = wsInt[0];
  const void* src; int idx;
  if (i < O_WK2T) {                 // w1: (512x256) -> (256x512)
    int m = i / 131072; int j = i - m*131072;
    src = (m==0) ? P.wk1 : ((m==1) ? P.wq1 : P.wv1);
    int n = j >> 9, k = j & 511;
    idx = k*HIDW + n;
  } else if (i < O_UK1T) {          // w2: (256x128) -> (128x256)
    int m = (i - O_WK2T) / 32768; int j = (i - O_WK2T) - m*32768;
    src = (m==0) ? P.wk2 : ((m==1) ? P.wq2 : P.wv2);
    int n = j >> 8, k = j & 255;
    idx = k*ATTW + n;
  } else if (i < O_UK2T) {          // uk1: (128x256) -> (256x128)
    int j = i - O_UK1T; src = P.uk1;
    int n = j >> 7, k = j & 127;
    idx = k*HIDW + n;
  } else {                          // uk2: (256x128) -> (128x256)
    int j = i - O_UK2T; src = P.uk2;
    int n = j >> 8, k = j & 255;
    idx = k*ATTW + n;
  }
  float v = f32m ? ((const float*)src)[idx] : bf2f(((const ushort*)src)[idx]);
  wt[i] = f2bf(v);
}

// ---------- MFMA stage1: X rows (pads=0) @ W1t(256x512) + b1, relu -> hl[50 x hls] ----------
template<bool F32>
__device__ __forceinline__ void stage1_mfma(const void* __restrict__ X, int xb, int c,
                                            const ushort* __restrict__ Wt,
                                            const void* __restrict__ Bv,
                                            ushort* __restrict__ hl, int hls, int t)
{
  const int w = t >> 6, L = t & 63, quad = L >> 4, l16 = L & 15;
  f32x4 acc[4][4];
#pragma unroll
  for (int i = 0; i < 4; i++)
#pragma unroll
    for (int j = 0; j < 4; j++) acc[i][j] = (f32x4){0.f,0.f,0.f,0.f};

  bool va[4]; int rr[4];
#pragma unroll
  for (int mt = 0; mt < 4; mt++) {
    int row = mt*16 + l16;
    va[mt] = (row < c);
    rr[mt] = va[mt] ? row : 0;
  }
  const ushort* pB = Wt + (size_t)(w*64 + l16)*DIM + quad*8;

  for (int k0 = 0; k0 < DIM; k0 += 32) {
    s16x8 a[4];
#pragma unroll
    for (int mt = 0; mt < 4; mt++) {
      s16x8 z = {};
      if (va[mt]) {
        if (F32) {
          const float* xp = (const float*)X + xb + rr[mt]*DIM + k0 + quad*8;
          s16x8 v;
#pragma unroll
          for (int j = 0; j < 8; j++) v[j] = (short)f2bf(xp[j]);
          a[mt] = v;
        } else {
          a[mt] = ldfrag((const ushort*)X + xb + rr[mt]*DIM + k0 + quad*8);
        }
      } else a[mt] = z;
    }
#pragma unroll
    for (int nt = 0; nt < 4; nt++) {
      s16x8 b = ldfrag(pB + (size_t)nt*16*DIM + k0);
#pragma unroll
      for (int mt = 0; mt < 4; mt++)
        acc[mt][nt] = mfma16(a[mt], b, acc[mt][nt]);
    }
  }
#pragma unroll
  for (int nt = 0; nt < 4; nt++) {
    int col = w*64 + nt*16 + l16;
    float bb = ld<F32>(Bv, col);
#pragma unroll
    for (int mt = 0; mt < 4; mt++)
#pragma unroll
      for (int r = 0; r < 4; r++) {
        int row = mt*16 + quad*4 + r;
        if (row < MAXC)
          hl[row*hls + col] = f2bf(fmaxf(acc[mt][nt][r] + bb, 0.f));
      }
  }
}

// ---------- MFMA stage2: hl(50 x HL2) @ W2t(128x256) + b2 -> dst(50 x BUFW) ----------
template<bool F32>
__device__ __forceinline__ void stage2_mfma(const ushort* __restrict__ hl,
                                            const ushort* __restrict__ W2t,
                                            const void* __restrict__ Bv,
                                            ushort* __restrict__ dst, int t)
{
  const int w = t >> 6, L = t & 63, quad = L >> 4, l16 = L & 15;
  f32x4 acc[4][2];
#pragma unroll
  for (int i = 0; i < 4; i++) { acc[i][0] = (f32x4){0.f,0.f,0.f,0.f}; acc[i][1] = (f32x4){0.f,0.f,0.f,0.f}; }
  const ushort* pB = W2t + (size_t)(w*32 + l16)*HIDW + quad*8;
  for (int k0 = 0; k0 < HIDW; k0 += 32) {
    s16x8 b0 = ldfrag(pB + k0);
    s16x8 b1 = ldfrag(pB + (size_t)16*HIDW + k0);
#pragma unroll
    for (int mt = 0; mt < 4; mt++) {
      s16x8 a = ldfrag(hl + (mt*16 + l16)*HL2 + k0 + quad*8);  // rows>=50 read junk, discarded
      acc[mt][0] = mfma16(a, b0, acc[mt][0]);
      acc[mt][1] = mfma16(a, b1, acc[mt][1]);
    }
  }
#pragma unroll
  for (int nt = 0; nt < 2; nt++) {
    int col = w*32 + nt*16 + l16;
    float bb = ld<F32>(Bv, col);
#pragma unroll
    for (int mt = 0; mt < 4; mt++)
#pragma unroll
      for (int r = 0; r < 4; r++) {
        int row = mt*16 + quad*4 + r;
        if (row < MAXC)
          dst[row*BUFW + col] = f2bf(acc[mt][nt][r] + bb);
      }
  }
}

// ---------- MFMA K2-stage1: src(50 x BUFW) @ W1t(256x128) + b, relu -> hl(50 x HL2) ----------
template<bool F32>
__device__ __forceinline__ void s1l_mfma(const ushort* __restrict__ src,
                                         const ushort* __restrict__ W1t,
                                         const void* __restrict__ Bv,
                                         ushort* __restrict__ hl, int t)
{
  const int w = t >> 6, L = t & 63, quad = L >> 4, l16 = L & 15;
  f32x4 acc[4][4];
#pragma unroll
  for (int i = 0; i < 4; i++)
#pragma unroll
    for (int j = 0; j < 4; j++) acc[i][j] = (f32x4){0.f,0.f,0.f,0.f};
  const ushort* pB = W1t + (size_t)(w*64 + l16)*ATTW + quad*8;
  for (int k0 = 0; k0 < ATTW; k0 += 32) {
    s16x8 b[4];
#pragma unroll
    for (int nt = 0; nt < 4; nt++) b[nt] = ldfrag(pB + (size_t)nt*16*ATTW + k0);
#pragma unroll
    for (int mt = 0; mt < 4; mt++) {
      s16x8 a = ldfrag(src + (mt*16 + l16)*BUFW + k0 + quad*8);  // rows>=50 junk, discarded
#pragma unroll
      for (int nt = 0; nt < 4; nt++)
        acc[mt][nt] = mfma16(a, b[nt], acc[mt][nt]);
    }
  }
#pragma unroll
  for (int nt = 0; nt < 4; nt++) {
    int col = w*64 + nt*16 + l16;
    float bb = ld<F32>(Bv, col);
#pragma unroll
    for (int mt = 0; mt < 4; mt++)
#pragma unroll
      for (int r = 0; r < 4; r++) {
        int row = mt*16 + quad*4 + r;
        if (row < MAXC)
          hl[row*HL2 + col] = f2bf(fmaxf(acc[mt][nt][r] + bb, 0.f));
      }
  }
}

// ---------- scalar helpers (VERBATIM r7, for fallback tiers) ----------
template<bool F32>
__device__ void stage1_g(const void* X, int xb, int c,
                         const void* W, const void* Bv, ushort* hl, int t)
{
  for (int r0 = 0; r0 < MAXC; r0 += CH) {
    float acc[CH];
#pragma unroll
    for (int i = 0; i < CH; i++) acc[i] = 0.f;
    for (int k = 0; k < DIM; k++) {
      float wv = ld<F32>(W, k*HIDW + t);
#pragma unroll
      for (int i = 0; i < CH; i++) {
        int m = r0 + i;
        int mc = (m < c) ? m : 0;
        float xv = ld<F32>(X, xb + mc*DIM + k);
        acc[i] += ((m < c) ? xv : 0.f) * wv;
      }
    }
    float bb = ld<F32>(Bv, t);
#pragma unroll
    for (int i = 0; i < CH; i++)
      hl[(r0+i)*HIDW + t] = f2bf(fmaxf(acc[i] + bb, 0.f));
  }
}

template<bool F32>
__device__ void stage1_l(const ushort* S, const void* W, const void* Bv,
                         ushort* hl, int t)
{
  for (int r0 = 0; r0 < MAXC; r0 += CH) {
    float acc[CH];
#pragma unroll
    for (int i = 0; i < CH; i++) acc[i] = 0.f;
    for (int k = 0; k < ATTW; k++) {
      float wv = ld<F32>(W, k*HIDW + t);
#pragma unroll
      for (int i = 0; i < CH; i++)
        acc[i] += bf2f(S[(r0+i)*BUFW + k]) * wv;
    }
    float bb = ld<F32>(Bv, t);
#pragma unroll
    for (int i = 0; i < CH; i++)
      hl[(r0+i)*HIDW + t] = f2bf(fmaxf(acc[i] + bb, 0.f));
  }
}

template<bool F32>
__device__ void stage2(const void* W, const void* Bv, const ushort* hlp,
                       ushort* dst, int t)
{
  const int col = t & (ATTW-1);
  const int h = t >> 7;
  float bb = ld<F32>(Bv, col);
  for (int m = h; m < MAXC; m += 2) {
    float a = 0.f;
    for (int k = 0; k < HIDW; k++)
      a += bf2f(hlp[m*HIDW + k]) * ld<F32>(W, k*ATTW + col);
    dst[m*BUFW + col] = f2bf(a + bb);
  }
}

// ================= tier-1 body: MFMA everywhere GEMM-shaped =================
template<bool F32>
__device__ void body_v2(const P27& P, int b, int t, char* smem,
                        int offset, int c, const ushort* wt)
{
  ushort* hl   = (ushort*)smem;                 // 50*264 elems = 26400 B
  ushort* buf0 = (ushort*)(smem + 26400);       // 50*136 elems = 13600 B
  ushort* buf1 = (ushort*)(smem + 40000);       // 13600 B
  float*  sb   = (float*)(smem + 53600);        // 2600 f32 = 10400 B (ends 64000)
  float* q2h  = sb;          // aliases: live only after attn is dead
  float* q2   = sb + 256;
  float* lgt  = sb + 384;
  float* selh = sb + 448;

  const int xb = offset * DIM;

  // K
  stage1_mfma<F32>(P.nodeH, xb, c, wt + O_WK1T, P.bk1, hl, HL2, t);
  __syncthreads();
  stage2_mfma<F32>(hl, wt + O_WK2T, P.bk2, buf0, t);
  __syncthreads();
  // Q
  stage1_mfma<F32>(P.nodeH, xb, c, wt + O_WQ1T, P.bq1, hl, HL2, t);
  __syncthreads();
  stage2_mfma<F32>(hl, wt + O_WQ2T, P.bq2, buf1, t);
  __syncthreads();

  // scores (verbatim r7 scalar)
  for (int idx = t; idx < MAXC*MAXC; idx += BLK) {
    int m = idx / MAXC, n = idx - m*MAXC;
    float s;
    if (m < c && n < c) {
      s = 0.f;
      for (int k = 0; k < ATTW; k++)
        s += bf2f(buf0[m*BUFW + k]) * bf2f(buf1[n*BUFW + k]);
    } else s = -1e9f;
    sb[m*SB_W + n] = s * SCL;
  }
  __syncthreads();
  if (t < MAXC) {
    float* row = sb + t*SB_W;
    float mx = row[0];
    for (int n = 1; n < MAXC; n++) mx = fmaxf(mx, row[n]);
    float sum = 0.f;
    for (int n = 0; n < MAXC; n++) { float e = expf(row[n] - mx); row[n] = e; sum += e; }
    float inv = 1.f / sum;
    for (int n = 0; n < MAXC; n++) row[n] *= inv;
  }
  __syncthreads();

  // V
  stage1_mfma<F32>(P.nodeH, xb, c, wt + O_WV1T, P.bv1, hl, HL2, t);
  __syncthreads();
  stage2_mfma<F32>(hl, wt + O_WV2T, P.bv2, buf0, t);
  __syncthreads();

  // corr = attn @ V -> buf1 (verbatim r7 scalar)
  {
    const int col = t & (ATTW-1);
    const int h = t >> 7;
    for (int m = h; m < MAXC; m += 2) {
      float a = 0.f;
      for (int n = 0; n < MAXC; n++)
        a += sb[m*SB_W + n] * bf2f(buf0[n*BUFW + col]);
      buf1[m*BUFW + col] = f2bf(a);
    }
  }
  __syncthreads();

  // K2 (both stages MFMA)
  s1l_mfma<F32>(buf1, wt + O_UK1T, P.ubk1, hl, t);
  __syncthreads();
  stage2_mfma<F32>(hl, wt + O_UK2T, P.ubk2, buf0, t);
  __syncthreads();

  // Q2 (verbatim r7 scalar)
  {
    float a = 0.f;
    for (int k = 0; k < DIM; k++)
      a += ld<F32>(P.molA, b*DIM + k) * ld<F32>(P.uq1, k*HIDW + t);
    q2h[t] = fmaxf(a + ld<F32>(P.ubq1, t), 0.f);
  }
  __syncthreads();
  if (t < ATTW) {
    float a = 0.f;
    for (int k = 0; k < HIDW; k++)
      a += q2h[k] * ld<F32>(P.uq2, k*ATTW + t);
    q2[t] = a + ld<F32>(P.ubq2, t);
  }
  __syncthreads();
  if (t < MAXC) {
    float s = 0.f;
    for (int k = 0; k < ATTW; k++)
      s += bf2f(buf0[t*BUFW + k]) * q2[k];
    lgt[t] = s * SCL;
  }
  __syncthreads();
  if (t < ATTW) {
    float a = 0.f;
    for (int k = 0; k < MAXC; k++)
      a += lgt[k] * ld<F32>(P.cs1, k*ATTW + t);
    selh[t] = fmaxf(a + ld<F32>(P.bcs1, t), 0.f);
  }
  __syncthreads();
  if (t < c) {
    float a = 0.f;
    for (int k = 0; k < ATTW; k++)
      a += selh[k] * ld<F32>(P.cs2, k*MAXC + t);
    a += ld<F32>(P.bcs2, t);
    float v = 1.f / (1.f + expf(-a));
    if (F32) ((float*)P.out)[offset + t] = v;
    else     ((ushort*)P.out)[offset + t] = f2bf(v);
  }
}

__global__ void fused_v2(P27 P, const int* __restrict__ wsInt, const ushort* __restrict__ wt)
{
  __shared__ __align__(16) char smem[64000];
  const int t = threadIdx.x, b = blockIdx.x;
  const int f32m = wsInt[0];
  const int offset = wsInt[4 + b];
  const int c = P.counts[b];
  if (f32m) body_v2<true >(P, b, t, smem, offset, c, wt);
  else      body_v2<false>(P, b, t, smem, offset, c, wt);
}

// ================= tier-2 body: VERBATIM r7 (stage1-only MFMA) =================
template<bool F32, bool MF>
__device__ void body(const P27& P, int b, int t,
                     ushort* hl, ushort* buf0, ushort* buf1, float* sb,
                     float* q2h, float* q2, float* logit, float* selh,
                     int offset, int c, const ushort* wt)
{
  const int xb = offset * DIM;

  if (MF) stage1_mfma<F32>(P.nodeH, xb, c, wt + O_WK1T, P.bk1, hl, HIDW, t);
  else    stage1_g<F32>(P.nodeH, xb, c, P.wk1, P.bk1, hl, t);
  __syncthreads();
  stage2<F32>(P.wk2, P.bk2, hl, buf0, t);
  __syncthreads();
  if (MF) stage1_mfma<F32>(P.nodeH, xb, c, wt + O_WQ1T, P.bq1, hl, HIDW, t);
  else    stage1_g<F32>(P.nodeH, xb, c, P.wq1, P.bq1, hl, t);
  __syncthreads();
  stage2<F32>(P.wq2, P.bq2, hl, buf1, t);
  __syncthreads();

  for (int idx = t; idx < MAXC*MAXC; idx += BLK) {
    int m = idx / MAXC, n = idx - m*MAXC;
    float s;
    if (m < c && n < c) {
      s = 0.f;
      for (int k = 0; k < ATTW; k++)
        s += bf2f(buf0[m*BUFW + k]) * bf2f(buf1[n*BUFW + k]);
    } else s = -1e9f;
    sb[m*SB_W + n] = s * SCL;
  }
  __syncthreads();
  if (t < MAXC) {
    float* row = sb + t*SB_W;
    float mx = row[0];
    for (int n = 1; n < MAXC; n++) mx = fmaxf(mx, row[n]);
    float sum = 0.f;
    for (int n = 0; n < MAXC; n++) { float e = expf(row[n] - mx); row[n] = e; sum += e; }
    float inv = 1.f / sum;
    for (int n = 0; n < MAXC; n++) row[n] *= inv;
  }
  __syncthreads();

  if (MF) stage1_mfma<F32>(P.nodeH, xb, c, wt + O_WV1T, P.bv1, hl, HIDW, t);
  else    stage1_g<F32>(P.nodeH, xb, c, P.wv1, P.bv1, hl, t);
  __syncthreads();
  stage2<F32>(P.wv2, P.bv2, hl, buf0, t);
  __syncthreads();

  {
    const int col = t & (ATTW-1);
    const int h = t >> 7;
    for (int m = h; m < MAXC; m += 2) {
      float a = 0.f;
      for (int n = 0; n < MAXC; n++)
        a += sb[m*SB_W + n] * bf2f(buf0[n*BUFW + col]);
      buf1[m*BUFW + col] = f2bf(a);
    }
  }
  __syncthreads();

  stage1_l<F32>(buf1, P.uk1, P.ubk1, hl, t);
  __syncthreads();
  stage2<F32>(P.uk2, P.ubk2, hl, buf0, t);
  __syncthreads();

  {
    float a = 0.f;
    for (int k = 0; k < DIM; k++)
      a += ld<F32>(P.molA, b*DIM + k) * ld<F32>(P.uq1, k*HIDW + t);
    q2h[t] = fmaxf(a + ld<F32>(P.ubq1, t), 0.f);
  }
  __syncthreads();
  if (t < ATTW) {
    float a = 0.f;
    for (int k = 0; k < HIDW; k++)
      a += q2h[k] * ld<F32>(P.uq2, k*ATTW + t);
    q2[t] = a + ld<F32>(P.ubq2, t);
  }
  __syncthreads();
  if (t < MAXC) {
    float s = 0.f;
    for (int k = 0; k < ATTW; k++)
      s += bf2f(buf0[t*BUFW + k]) * q2[k];
    logit[t] = s * SCL;
  }
  __syncthreads();
  if (t < ATTW) {
    float a = 0.f;
    for (int k = 0; k < MAXC; k++)
      a += logit[k] * ld<F32>(P.cs1, k*ATTW + t);
    selh[t] = fmaxf(a + ld<F32>(P.bcs1, t), 0.f);
  }
  __syncthreads();
  if (t < c) {
    float a = 0.f;
    for (int k = 0; k < ATTW; k++)
      a += selh[k] * ld<F32>(P.cs2, k*MAXC + t);
    a += ld<F32>(P.bcs2, t);
    float v = 1.f / (1.f + expf(-a));
    if (F32) ((float*)P.out)[offset + t] = v;
    else     ((ushort*)P.out)[offset + t] = f2bf(v);
  }
}

__global__ void fused_mfma(P27 P, const int* __restrict__ wsInt, const ushort* __restrict__ wt)
{
  __shared__ __align__(16) ushort hl  [MAXC*HIDW];
  __shared__ __align__(16) ushort buf0[MAXC*BUFW];
  __shared__ __align__(16) ushort buf1[MAXC*BUFW];
  __shared__ __align__(16) float  sb  [MAXC*SB_W];
  __shared__ __align__(16) float  q2h [HIDW];
  __shared__ __align__(16) float  q2  [ATTW];
  __shared__ __align__(16) float  logit[64];
  __shared__ __align__(16) float  selh[ATTW];
  const int t = threadIdx.x, b = blockIdx.x;
  const int f32m = wsInt[0];
  const int offset = wsInt[4 + b];
  const int c = P.counts[b];
  if (f32m) body<true , true>(P, b, t, hl, buf0, buf1, sb, q2h, q2, logit, selh, offset, c, wt);
  else      body<false, true>(P, b, t, hl, buf0, buf1, sb, q2h, q2, logit, selh, offset, c, wt);
}

__global__ void fused_scalar(P27 P, const int* __restrict__ wsInt)
{
  __shared__ __align__(16) ushort hl  [MAXC*HIDW];
  __shared__ __align__(16) ushort buf0[MAXC*BUFW];
  __shared__ __align__(16) ushort buf1[MAXC*BUFW];
  __shared__ __align__(16) float  sb  [MAXC*SB_W];
  __shared__ __align__(16) float  q2h [HIDW];
  __shared__ __align__(16) float  q2  [ATTW];
  __shared__ __align__(16) float  logit[64];
  __shared__ __align__(16) float  selh[ATTW];
  const int t = threadIdx.x, b = blockIdx.x;
  const int f32m = wsInt[0];
  const int offset = wsInt[4 + b];
  const int c = P.counts[b];
  if (f32m) body<true , false>(P, b, t, hl, buf0, buf1, sb, q2h, q2, logit, selh, offset, c, nullptr);
  else      body<false, false>(P, b, t, hl, buf0, buf1, sb, q2h, q2, logit, selh, offset, c, nullptr);
}

extern "C" void kernel_launch(void* const* d_in, const int* in_sizes, int n_in,
                              void* d_out, int out_size, void* d_ws, size_t ws_size,
                              hipStream_t stream) {
  P27 P;
  P.molA  = d_in[0];
  P.nodeH = d_in[1];
  P.counts= (const int*)d_in[2];
  P.wq1 = d_in[3];  P.bq1 = d_in[4];  P.wq2 = d_in[5];  P.bq2 = d_in[6];
  P.wk1 = d_in[7];  P.bk1 = d_in[8];  P.wk2 = d_in[9];  P.bk2 = d_in[10];
  P.wv1 = d_in[11]; P.bv1 = d_in[12]; P.wv2 = d_in[13]; P.bv2 = d_in[14];
  P.uk1 = d_in[15]; P.ubk1= d_in[16]; P.uk2 = d_in[17]; P.ubk2= d_in[18];
  P.uq1 = d_in[19]; P.ubq1= d_in[20]; P.uq2 = d_in[21]; P.ubq2= d_in[22];
  P.cs1 = d_in[23]; P.bcs1= d_in[24]; P.cs2 = d_in[25]; P.bcs2= d_in[26];
  P.out = d_out;
  const int nb = in_sizes[2];
  int* wsInt = (int*)d_ws;

  prep_kernel<<<dim3(1), dim3(BLK), 0, stream>>>((const ushort*)d_in[0],
                                                 (const int*)d_in[2], nb, wsInt);

  const size_t need1 = (size_t)WT_BYTE_OFF + (size_t)WT_ELEMS * 2;
  const size_t need2 = (size_t)WT_BYTE_OFF + (size_t)WT_T2ELEMS * 2;
  if (ws_size >= need2) {
    ushort* wt = (ushort*)((char*)d_ws + WT_BYTE_OFF);
    unsigned long long cap = (ws_size - WT_BYTE_OFF) / 2;
    transpose_wt<<<dim3((WT_ELEMS + BLK - 1)/BLK), dim3(BLK), 0, stream>>>(P, wsInt, wt, cap);
    if (ws_size >= need1)
      fused_v2<<<dim3(nb), dim3(BLK), 0, stream>>>(P, wsInt, wt);
    else
      fused_mfma<<<dim3(nb), dim3(BLK), 0, stream>>>(P, wsInt, wt);
  } else {
    fused_scalar<<<dim3(nb), dim3(BLK), 0, stream>>>(P, wsInt);
  }
}